// Round 17
// baseline (276.701 us; speedup 1.0000x reference)
//
#include <hip/hip_runtime.h>
#include <stdint.h>

#define TPB 512
#define BM 32
#define CTXD 256
#define HID 128
#define TSTEPS 48
#define DTC (1.0f/30.0f)

typedef short short8 __attribute__((ext_vector_type(8)));
typedef float f32x4 __attribute__((ext_vector_type(4)));
typedef float f32x2 __attribute__((ext_vector_type(2)));

// ---------------- LDS layout (bytes) — 94.5 KB, 1 block/CU, 8 waves ----------------
// W_Z / W_N / h tiles: row stride 256B, XOR swizzle byte ^= (row&15)<<4.
#define OFF_WZ   0        // W_hh Z bf16 [128][128]
#define OFF_WN   32768    // W_hh N bf16 [128][128]
#define OFF_H    65536    // loop: 2 x h bf16 [32][256B] (8K each); phase A: ctx [32][512B] (16K)
#define HBUFSZ   8192
#define CSTRIDE  512
#define OFF_GIN  81920    // gi_n f16-packed per-thread [512][16B] (own-slot)
#define OFF_WD   90112    // 6 f32[128] tables: wdr0,wdr1,wdz0,wdz1,wdn0,wdn1
#define OFF_BHN  93184    // bhh_n f32[128]
#define OFF_TB1  93696    // b1 f32[64]
#define OFF_TW2  93952    // W2 f32[2][64]
#define LDS_BYTES 94464

__device__ __forceinline__ uint32_t cvtpk_bf16(float lo, float hi) {
    uint32_t r;
    asm("v_cvt_pk_bf16_f32 %0, %1, %2" : "=v"(r) : "v"(lo), "v"(hi));
    return r;
}
__device__ __forceinline__ uint32_t pkh2(float a, float b) {
    union { _Float16 h[2]; uint32_t u; } v;
    v.h[0] = (_Float16)a; v.h[1] = (_Float16)b; return v.u;
}
__device__ __forceinline__ float h2lo(uint32_t u) {
    union { uint32_t u; _Float16 h[2]; } v; v.u = u; return (float)v.h[0];
}
__device__ __forceinline__ float h2hi(uint32_t u) {
    union { uint32_t u; _Float16 h[2]; } v; v.u = u; return (float)v.h[1];
}
__device__ __forceinline__ float fsigm(float x) {
    return __builtin_amdgcn_rcpf(1.0f + __expf(-x));
}
__device__ __forceinline__ float ftanhf(float x) {
    return fmaf(-2.0f, __builtin_amdgcn_rcpf(1.0f + __expf(2.0f * x)), 1.0f);
}
__device__ __forceinline__ short8 ldA8(const float* src) {
    f32x2 v0 = *(const f32x2*)(src + 0);
    f32x2 v1 = *(const f32x2*)(src + 2);
    f32x2 v2 = *(const f32x2*)(src + 4);
    f32x2 v3 = *(const f32x2*)(src + 6);
    union { short8 s; uint32_t u[4]; } r;
    r.u[0] = cvtpk_bf16(v0.x, v0.y);
    r.u[1] = cvtpk_bf16(v1.x, v1.y);
    r.u[2] = cvtpk_bf16(v2.x, v2.y);
    r.u[3] = cvtpk_bf16(v3.x, v3.y);
    return r.s;
}

// SINGLE-BARRIER SCHEDULE (R16 conclusion: occupancy is not the lever; the
// 2-barrier lockstep is). MLP made intra-wave: every wave computes the FULL
// MLP for both row-tiles with W1 register-resident (B-frags reuse the h frags
// already loaded) -> delta via in-wave shfl_xor, so the partials barrier and
// the 49th tail iteration disappear. One __syncthreads per step, protecting
// only the h_t -> h_{t+1} swap. 8 waves/CU at proven (512,2).
__global__ __launch_bounds__(TPB, 2)
void dd_kernel(const float* __restrict__ ctx, const float* __restrict__ lv,
               const float* __restrict__ Winit, const float* __restrict__ binit,
               const float* __restrict__ Wih, const float* __restrict__ bih,
               const float* __restrict__ Whh, const float* __restrict__ bhh,
               const float* __restrict__ W1, const float* __restrict__ b1,
               const float* __restrict__ W2, const float* __restrict__ b2,
               float* __restrict__ out)
{
    extern __shared__ char smem[];
    const int tid  = threadIdx.x;
    const int w    = tid >> 6;          // wave 0..7; owns GRU unit-tile 16w..16w+15, both row-tiles
    const int lane = tid & 63;
    const int g    = (lane >> 4) & 3;
    const int l15  = lane & 15;
    const int row0 = blockIdx.x * BM;
    const int swz  = l15 << 4;

    // ---------------- stage LDS ----------------
    for (int p = tid; p < 128 * 64; p += TPB) {           // W_hh Z rows 128..255
        int u = p >> 6, kp = p & 63;
        f32x2 v = *(const f32x2*)(Whh + (size_t)(128 + u) * HID + 2 * kp);
        *(uint32_t*)(smem + OFF_WZ + u * 256 + ((4 * kp) ^ ((u & 15) << 4))) = cvtpk_bf16(v.x, v.y);
    }
    for (int p = tid; p < 128 * 64; p += TPB) {           // W_hh N rows 256..383
        int u = p >> 6, kp = p & 63;
        f32x2 v = *(const f32x2*)(Whh + (size_t)(256 + u) * HID + 2 * kp);
        *(uint32_t*)(smem + OFF_WN + u * 256 + ((4 * kp) ^ ((u & 15) << 4))) = cvtpk_bf16(v.x, v.y);
    }
    for (int p = tid; p < 32 * 128; p += TPB) {           // ctx (phase A, stride 512)
        int r = p >> 7, kp = p & 127;
        f32x2 v = *(const f32x2*)(ctx + (size_t)(row0 + r) * CTXD + 2 * kp);
        *(uint32_t*)(smem + OFF_H + r * CSTRIDE + ((4 * kp) ^ ((r & 15) << 4))) = cvtpk_bf16(v.x, v.y);
    }
    if (tid < 128) {                                      // f32 tables
        int u = tid;
        ((float*)(smem + OFF_WD +    0))[u] = Wih[(size_t)u * 258 + 0];
        ((float*)(smem + OFF_WD +  512))[u] = Wih[(size_t)u * 258 + 1];
        ((float*)(smem + OFF_WD + 1024))[u] = Wih[(size_t)(128 + u) * 258 + 0];
        ((float*)(smem + OFF_WD + 1536))[u] = Wih[(size_t)(128 + u) * 258 + 1];
        ((float*)(smem + OFF_WD + 2048))[u] = Wih[(size_t)(256 + u) * 258 + 0];
        ((float*)(smem + OFF_WD + 2560))[u] = Wih[(size_t)(256 + u) * 258 + 1];
        ((float*)(smem + OFF_BHN))[u] = bhh[256 + u];
        ((float*)(smem + OFF_TW2))[u] = W2[u];
    }
    if (tid < 64) ((float*)(smem + OFF_TB1))[tid] = b1[tid];

    const int u16 = 16 * w + l15;
    const float b2c0 = b2[0], b2c1 = b2[1];
    float dx[2], dy[2], pos0[2], pos1[2];
#pragma unroll
    for (int m = 0; m < 2; ++m) {
        f32x2 v = *(const f32x2*)(lv + (size_t)(row0 + 16 * m + l15) * 2);
        dx[m] = v.x * DTC; dy[m] = v.y * DTC;
        pos0[m] = 0.f; pos1[m] = 0.f;
    }

    __syncthreads();

    // ---------------- Phase A: gi tile + h0 (unit-tile w x both row-tiles) ----------------
    f32x4 zero4 = {0.f, 0.f, 0.f, 0.f};
    f32x4 accA[4][2];
#pragma unroll
    for (int jl = 0; jl < 4; ++jl) { accA[jl][0] = zero4; accA[jl][1] = zero4; }

    for (int kk = 0; kk < 8; ++kk) {
        const int cx = (64 * kk + 16 * g);
        short8 bf0 = *(const short8*)(smem + OFF_H + l15 * CSTRIDE + (cx ^ swz));
        short8 bf1 = *(const short8*)(smem + OFF_H + (16 + l15) * CSTRIDE + (cx ^ swz));
        short8 afR = ldA8(Wih + (size_t)u16 * 258 + 2 + 32 * kk + 8 * g);
        short8 afZ = ldA8(Wih + (size_t)(128 + u16) * 258 + 2 + 32 * kk + 8 * g);
        short8 afN = ldA8(Wih + (size_t)(256 + u16) * 258 + 2 + 32 * kk + 8 * g);
        short8 afH = ldA8(Winit + (size_t)u16 * 256 + 32 * kk + 8 * g);
        accA[0][0] = __builtin_amdgcn_mfma_f32_16x16x32_bf16(afR, bf0, accA[0][0], 0, 0, 0);
        accA[0][1] = __builtin_amdgcn_mfma_f32_16x16x32_bf16(afR, bf1, accA[0][1], 0, 0, 0);
        accA[1][0] = __builtin_amdgcn_mfma_f32_16x16x32_bf16(afZ, bf0, accA[1][0], 0, 0, 0);
        accA[1][1] = __builtin_amdgcn_mfma_f32_16x16x32_bf16(afZ, bf1, accA[1][1], 0, 0, 0);
        accA[2][0] = __builtin_amdgcn_mfma_f32_16x16x32_bf16(afN, bf0, accA[2][0], 0, 0, 0);
        accA[2][1] = __builtin_amdgcn_mfma_f32_16x16x32_bf16(afN, bf1, accA[2][1], 0, 0, 0);
        accA[3][0] = __builtin_amdgcn_mfma_f32_16x16x32_bf16(afH, bf0, accA[3][0], 0, 0, 0);
        accA[3][1] = __builtin_amdgcn_mfma_f32_16x16x32_bf16(afH, bf1, accA[3][1], 0, 0, 0);
    }

    // gi pack (f16): R,Z regs; N -> LDS own-slot. h0 master f32.
    uint32_t gipR[2][2], gipZ[2][2];
    float hm[2][4];
    {
        float tbr[4], tbz[4], tbn[4], thi[4];
#pragma unroll
        for (int r = 0; r < 4; ++r) {
            int u = 16 * w + 4 * g + r;
            tbr[r] = bih[u] + bhh[u];
            tbz[r] = bih[128 + u] + bhh[128 + u];
            tbn[r] = bih[256 + u];
            thi[r] = binit[u];
        }
        uint4 gn4;
        gn4.x = pkh2(accA[2][0][0] + tbn[0], accA[2][0][1] + tbn[1]);
        gn4.y = pkh2(accA[2][0][2] + tbn[2], accA[2][0][3] + tbn[3]);
        gn4.z = pkh2(accA[2][1][0] + tbn[0], accA[2][1][1] + tbn[1]);
        gn4.w = pkh2(accA[2][1][2] + tbn[2], accA[2][1][3] + tbn[3]);
        *(uint4*)(smem + OFF_GIN + tid * 16) = gn4;       // own slot; no barrier needed
#pragma unroll
        for (int m = 0; m < 2; ++m) {
            gipR[m][0] = pkh2(accA[0][m][0] + tbr[0], accA[0][m][1] + tbr[1]);
            gipR[m][1] = pkh2(accA[0][m][2] + tbr[2], accA[0][m][3] + tbr[3]);
            gipZ[m][0] = pkh2(accA[1][m][0] + tbz[0], accA[1][m][1] + tbz[1]);
            gipZ[m][1] = pkh2(accA[1][m][2] + tbz[2], accA[1][m][3] + tbz[3]);
#pragma unroll
            for (int r = 0; r < 4; ++r)
                hm[m][r] = ftanhf(accA[3][m][r] + thi[r]);
        }
    }

    // register-resident weights, loaded AFTER phase A (loop-only lifetime):
    // W_R frags for this wave's unit-tile (16 VGPR) + FULL W1 (4 jt x 4 kk, 64 VGPR)
    short8 wfr[4], wf1[4][4];
#pragma unroll
    for (int kk = 0; kk < 4; ++kk) {
        wfr[kk] = ldA8(Whh + (size_t)u16 * HID + 32 * kk + 8 * g);
#pragma unroll
        for (int jt = 0; jt < 4; ++jt)
            wf1[jt][kk] = ldA8(W1 + (size_t)(16 * jt + l15) * HID + 32 * kk + 8 * g);
    }

    __syncthreads();              // ctx reads done; h region reusable

#pragma unroll
    for (int m = 0; m < 2; ++m) {  // h0 -> buf0
        uint2 pk;
        pk.x = cvtpk_bf16(hm[m][0], hm[m][1]);
        pk.y = cvtpk_bf16(hm[m][2], hm[m][3]);
        *(uint2*)(smem + OFF_H + (16 * m + l15) * 256 + ((32 * w + 8 * g) ^ swz)) = pk;
    }
    __syncthreads();

    // h_t fragments (live across the iteration; reloaded after each barrier)
    short8 hf[2][4];
#pragma unroll
    for (int m = 0; m < 2; ++m)
#pragma unroll
        for (int kk = 0; kk < 4; ++kk)
            hf[m][kk] = *(const short8*)(smem + OFF_H + (16 * m + l15) * 256 + ((64 * kk + 16 * g) ^ swz));

    const int ub4 = (16 * w + 4 * g) * 4;

    // ---------------- 48-step recurrence — ONE barrier per step ----------------
    for (int t = 0; t < TSTEPS; ++t) {
        const int wbuf = OFF_H + ((t + 1) & 1) * HBUFSZ;   // h_{t+1} buffer
        // 1) GRU preacts on h_t
        f32x4 aR[2], aZ[2], aN[2];
        {
            f32x4 bh = *(const f32x4*)(smem + OFF_BHN + ub4);
#pragma unroll
            for (int m = 0; m < 2; ++m) {
                aR[m][0] = h2lo(gipR[m][0]); aR[m][1] = h2hi(gipR[m][0]);
                aR[m][2] = h2lo(gipR[m][1]); aR[m][3] = h2hi(gipR[m][1]);
                aZ[m][0] = h2lo(gipZ[m][0]); aZ[m][1] = h2hi(gipZ[m][0]);
                aZ[m][2] = h2lo(gipZ[m][1]); aZ[m][3] = h2hi(gipZ[m][1]);
                aN[m] = bh;
            }
        }
#pragma unroll
        for (int kk = 0; kk < 4; ++kk) {
            const int cx = (64 * kk + 16 * g) ^ swz;
            short8 fZ = *(const short8*)(smem + OFF_WZ + u16 * 256 + cx);
            short8 fN = *(const short8*)(smem + OFF_WN + u16 * 256 + cx);
#pragma unroll
            for (int m = 0; m < 2; ++m) {
                aR[m] = __builtin_amdgcn_mfma_f32_16x16x32_bf16(wfr[kk], hf[m][kk], aR[m], 0, 0, 0);
                aZ[m] = __builtin_amdgcn_mfma_f32_16x16x32_bf16(fZ, hf[m][kk], aZ[m], 0, 0, 0);
                aN[m] = __builtin_amdgcn_mfma_f32_16x16x32_bf16(fN, hf[m][kk], aN[m], 0, 0, 0);
            }
        }
        // 2) gates (delta_t) -> h_{t+1}, write
        {
            f32x4 wr0 = *(const f32x4*)(smem + OFF_WD +    0 + ub4);
            f32x4 wr1 = *(const f32x4*)(smem + OFF_WD +  512 + ub4);
            f32x4 wz0 = *(const f32x4*)(smem + OFF_WD + 1024 + ub4);
            f32x4 wz1 = *(const f32x4*)(smem + OFF_WD + 1536 + ub4);
            f32x4 wn0 = *(const f32x4*)(smem + OFF_WD + 2048 + ub4);
            f32x4 wn1 = *(const f32x4*)(smem + OFF_WD + 2560 + ub4);
            uint4 gn4 = *(const uint4*)(smem + OFF_GIN + tid * 16);
            uint32_t gnu[4] = {gn4.x, gn4.y, gn4.z, gn4.w};
#pragma unroll
            for (int m = 0; m < 2; ++m) {
#pragma unroll
                for (int r = 0; r < 4; ++r) {
                    float rr  = fsigm(fmaf(dy[m], wr1[r], fmaf(dx[m], wr0[r], aR[m][r])));
                    float zz  = fsigm(fmaf(dy[m], wz1[r], fmaf(dx[m], wz0[r], aZ[m][r])));
                    float gnv = (r & 1) ? h2hi(gnu[2 * m + (r >> 1)]) : h2lo(gnu[2 * m + (r >> 1)]);
                    float inn = fmaf(dy[m], wn1[r], fmaf(dx[m], wn0[r], gnv));
                    float nn  = ftanhf(fmaf(rr, aN[m][r], inn));
                    hm[m][r]  = fmaf(zz, hm[m][r] - nn, nn);
                }
                uint2 pk;
                pk.x = cvtpk_bf16(hm[m][0], hm[m][1]);
                pk.y = cvtpk_bf16(hm[m][2], hm[m][3]);
                *(uint2*)(smem + wbuf + (16 * m + l15) * 256 + ((32 * w + 8 * g) ^ swz)) = pk;
            }
        }
        __syncthreads();          // THE barrier: h_{t+1} visible
        // 3) reload h frags (h_{t+1})
#pragma unroll
        for (int m = 0; m < 2; ++m)
#pragma unroll
            for (int kk = 0; kk < 4; ++kk)
                hf[m][kk] = *(const short8*)(smem + wbuf + (16 * m + l15) * 256 + ((64 * kk + 16 * g) ^ swz));
        // 4) intra-wave full MLP(h_{t+1}) -> delta_{t+1} (no barrier)
        float s0[2] = {0.f, 0.f}, s1[2] = {0.f, 0.f};
#pragma unroll
        for (int jt = 0; jt < 4; ++jt) {
            f32x4 a10 = zero4, a11 = zero4;
#pragma unroll
            for (int kk = 0; kk < 4; ++kk) {
                a10 = __builtin_amdgcn_mfma_f32_16x16x32_bf16(wf1[jt][kk], hf[0][kk], a10, 0, 0, 0);
                a11 = __builtin_amdgcn_mfma_f32_16x16x32_bf16(wf1[jt][kk], hf[1][kk], a11, 0, 0, 0);
            }
            const int um4 = (16 * jt + 4 * g) * 4;
            f32x4 b1v = *(const f32x4*)(smem + OFF_TB1 + um4);
            f32x4 w2a = *(const f32x4*)(smem + OFF_TW2 + um4);
            f32x4 w2b = *(const f32x4*)(smem + OFF_TW2 + 256 + um4);
#pragma unroll
            for (int r = 0; r < 4; ++r) {
                float h0v = fmaxf(a10[r] + b1v[r], 0.f);
                float h1v = fmaxf(a11[r] + b1v[r], 0.f);
                s0[0] = fmaf(h0v, w2a[r], s0[0]);
                s1[0] = fmaf(h0v, w2b[r], s1[0]);
                s0[1] = fmaf(h1v, w2a[r], s0[1]);
                s1[1] = fmaf(h1v, w2b[r], s1[1]);
            }
        }
#pragma unroll
        for (int m = 0; m < 2; ++m) {
            float a = s0[m], b = s1[m];
            a += __shfl_xor(a, 16, 64); a += __shfl_xor(a, 32, 64);
            b += __shfl_xor(b, 16, 64); b += __shfl_xor(b, 32, 64);
            a += b2c0; b += b2c1;
            dx[m] = a; dy[m] = b;
            pos0[m] += a; pos1[m] += b;
        }
        if (w == 0 && lane < 16) {
#pragma unroll
            for (int m = 0; m < 2; ++m) {
                f32x2 o2; o2.x = pos0[m]; o2.y = pos1[m];
                *(f32x2*)(out + (size_t)(row0 + 16 * m + l15) * (TSTEPS * 2) + 2 * t) = o2;
            }
        }
    }
}

extern "C" void kernel_launch(void* const* d_in, const int* in_sizes, int n_in,
                              void* d_out, int out_size, void* d_ws, size_t ws_size,
                              hipStream_t stream) {
    (void)in_sizes; (void)n_in; (void)d_ws; (void)ws_size; (void)out_size;
    const float* ctx   = (const float*)d_in[0];
    const float* lv    = (const float*)d_in[1];
    const float* Winit = (const float*)d_in[2];
    const float* binit = (const float*)d_in[3];
    const float* Wih   = (const float*)d_in[4];
    const float* bih   = (const float*)d_in[5];
    const float* Whh   = (const float*)d_in[6];
    const float* bhh   = (const float*)d_in[7];
    const float* W1    = (const float*)d_in[8];
    const float* b1    = (const float*)d_in[9];
    const float* W2    = (const float*)d_in[10];
    const float* b2    = (const float*)d_in[11];
    float* out = (float*)d_out;

    hipFuncSetAttribute(reinterpret_cast<const void*>(dd_kernel),
                        hipFuncAttributeMaxDynamicSharedMemorySize, LDS_BYTES);
    dd_kernel<<<16384 / BM, TPB, LDS_BYTES, stream>>>(
        ctx, lv, Winit, binit, Wih, bih, Whh, bhh, W1, b1, W2, b2, out);
}